// Round 4
// baseline (561.433 us; speedup 1.0000x reference)
//
#include <hip/hip_runtime.h>
#include <hip/hip_bf16.h>

// ---------------------------------------------------------------------------
// MLDecoder classification head, MI355X bf16-MFMA implementation.
// B=64, C_IN=2048, H=W=14 (S=196), D=768, FF=2048, G=100, NC=9605, NH=8, HD=96
// ---------------------------------------------------------------------------

#define B_    64
#define CIN_  2048
#define S_    196
#define D_    768
#define FF_   2048
#define G_    100
#define NC_   9605
#define NH_   8
#define HD_   96
#define DF_   97
#define FP_   112          // DF_ padded to 16
#define GP_   112          // G padded to 16
#define SP_   224          // S padded to 32 (7 K-steps) for P / V^T
#define BS_   (B_ * S_)   // 12544
#define BG_   (B_ * G_)   // 6400

typedef __bf16 bf16x8 __attribute__((ext_vector_type(8)));
typedef float  f32x4  __attribute__((ext_vector_type(4)));
typedef ushort us8    __attribute__((ext_vector_type(8)));

__device__ __forceinline__ float bf2f(ushort u) {
  union { unsigned int i; float f; } v; v.i = ((unsigned int)u) << 16; return v.f;
}
__device__ __forceinline__ ushort f2bf(float f) {
  __hip_bfloat16 h = __float2bfloat16(f);
  return *reinterpret_cast<ushort*>(&h);
}

// async global->LDS, 16 bytes per lane. LDS target must be wave-uniform base
// + lane*16 (our staging layouts satisfy this: lds byte offset == 16*i, i linear in t).
__device__ __forceinline__ void gl2lds16(const ushort* g, ushort* l) {
  __builtin_amdgcn_global_load_lds((const __attribute__((address_space(1))) unsigned int*)g,
                                   (__attribute__((address_space(3))) unsigned int*)l, 16, 0, 0);
}

// ---------------------------------------------------------------------------
// fused prep: dup-transpose + x-transpose + weight converts + tgt LN
// one dispatch, job selected by block range.
// ---------------------------------------------------------------------------
#define DT_BLKS 400    // dupT:  (g, d-chunk of 192)
#define XP_BLKS 2048   // xpose: (b, c-chunk of 64), full s
#define CV_BLKS 512    // cvt:   grid-stride, 8-float units
#define TG_BLKS 128    // tgt LN rows (padded)

struct PrepArgs {
  const float* x;   ushort* aemb;
  const float* dup; ushort* dupT;
  const float* csrc[7]; ushort* cdst[7]; int cn4[7]; int ctotal;  // counts in 8-float units
  const float* qe; const float* g1; const float* be1;
  float* tgt; ushort* tgtB;
};

__global__ __launch_bounds__(256) void k_prep(PrepArgs pa) {
  __shared__ __align__(16) char smem[196 * 72 * 2];   // 28224 B, unioned per job
  int jid = blockIdx.x;
  const int t = threadIdx.x;

  if (jid < DT_BLKS) {
    // dup_pool [g][d][f=97] -> dupT [g][f=112][d] bf16, f zero-padded.
    float (*tile)[33] = (float (*)[33])smem;
    const int g = jid >> 2, dchunk = jid & 3;
    const int tx = t & 31, ty = t >> 5;
    for (int di = 0; di < 6; ++di) {
      const int d0 = dchunk * 192 + di * 32;
      for (int f0 = 0; f0 < 128; f0 += 32) {
        #pragma unroll
        for (int r = 0; r < 32; r += 8) {
          int d = d0 + ty + r, f = f0 + tx;
          tile[ty + r][tx] = (f < DF_) ? pa.dup[(size_t)g * D_ * DF_ + (size_t)d * DF_ + f] : 0.f;
        }
        __syncthreads();
        #pragma unroll
        for (int r = 0; r < 32; r += 8) {
          int f = f0 + ty + r, d = d0 + tx;
          if (f < FP_) pa.dupT[((size_t)g * FP_ + f) * D_ + d] = f2bf(tile[tx][ty + r]);
        }
        __syncthreads();
      }
    }
    return;
  }
  jid -= DT_BLKS;

  if (jid < XP_BLKS) {
    // x [B][C][S] f32 -> aemb [(b,s)][C] bf16.
    ushort* xs = (ushort*)smem;
    const int b = jid >> 5, cbase = (jid & 31) * 64;
    const float* xb = pa.x + ((size_t)b * CIN_ + cbase) * S_;
    #pragma unroll
    for (int it = 0; it < 4; ++it) {
      const int u = it * 256 + t;
      if (u < 784) {                       // 49 s-quads x 16 c-quads
        const int j = u >> 4, cq = u & 15;
        const int s = 4 * j;
        float4 a[4];
        #pragma unroll
        for (int r = 0; r < 4; ++r)
          a[r] = *(const float4*)(xb + (size_t)(cq * 4 + r) * S_ + s);
        #pragma unroll
        for (int r = 0; r < 4; ++r) {
          ushort4 o;
          o.x = f2bf(((const float*)&a[0])[r]);
          o.y = f2bf(((const float*)&a[1])[r]);
          o.z = f2bf(((const float*)&a[2])[r]);
          o.w = f2bf(((const float*)&a[3])[r]);
          *(ushort4*)&xs[(s + r) * 72 + cq * 4] = o;
        }
      }
    }
    __syncthreads();
    const int sl = t >> 3, oct = t & 7;    // 8 lanes -> 128 B contiguous store
    #pragma unroll
    for (int sr = 0; sr < 7; ++sr) {
      const int s = sr * 32 + sl;
      if (s < S_) {
        us8 v = *(const us8*)&xs[s * 72 + oct * 8];
        *(us8*)&pa.aemb[((size_t)(b * S_ + s)) * CIN_ + cbase + oct * 8] = v;
      }
    }
    return;
  }
  jid -= XP_BLKS;

  if (jid < CV_BLKS) {
    // bulk fp32 -> bf16 weight converts, grid-stride over 7 segments,
    // 8 floats per unit: 32B read / 16B write per thread-iter.
    int i = jid * 256 + t;
    const int stride = CV_BLKS * 256;
    for (; i < pa.ctotal; i += stride) {
      int seg = 0, off = i;
      while (off >= pa.cn4[seg]) { off -= pa.cn4[seg]; ++seg; }
      const float4* sp = (const float4*)pa.csrc[seg];
      float4 v0 = sp[2 * off], v1 = sp[2 * off + 1];
      us8 o;
      o[0] = f2bf(v0.x); o[1] = f2bf(v0.y); o[2] = f2bf(v0.z); o[3] = f2bf(v0.w);
      o[4] = f2bf(v1.x); o[5] = f2bf(v1.y); o[6] = f2bf(v1.z); o[7] = f2bf(v1.w);
      ((us8*)pa.cdst[seg])[off] = o;
    }
    return;
  }
  jid -= CV_BLKS;

  // tgt = LN(2*query_embed)*g1 + be1 -> fp32 [100,768] + bf16 [128,768] (pad 0)
  float* r1 = (float*)smem;
  float* r2 = r1 + 256;
  const int g = jid;
  if (g >= G_) {
    for (int d = t; d < D_; d += 256) pa.tgtB[(size_t)g * D_ + d] = 0;
    return;
  }
  float y[3]; float s = 0.f, sq = 0.f;
  const float* row = pa.qe + (size_t)g * D_;
  #pragma unroll
  for (int i = 0; i < 3; ++i) { float v = 2.f * row[t + i * 256]; y[i] = v; s += v; sq += v * v; }
  r1[t] = s; r2[t] = sq; __syncthreads();
  for (int o = 128; o > 0; o >>= 1) { if (t < o) { r1[t] += r1[t + o]; r2[t] += r2[t + o]; } __syncthreads(); }
  const float mean = r1[0] * (1.f / D_);
  const float var  = r2[0] * (1.f / D_) - mean * mean;
  const float w = rsqrtf(var + 1e-5f);
  #pragma unroll
  for (int i = 0; i < 3; ++i) {
    int d = t + i * 256;
    float v = (y[i] - mean) * w * pa.g1[d] + pa.be1[d];
    pa.tgt[(size_t)g * D_ + d] = v;
    pa.tgtB[(size_t)g * D_ + d] = f2bf(v);
  }
}

// ---------------- bf16 MFMA GEMM core: C[M,N] = A[M,K]*B[N,K]^T + bias -----
// 128x128 tile, BK=32. R11 (T4+T5): counted-vmcnt two-barrier k-loop — the
// per-step __syncthreads() forced vmcnt(0)+lgkmcnt(0), re-serializing every
// step (m233's "2-phase stall"). Now: stage(next) -> vmcnt(4) [waits only
// cur's loads; prefetch stays in flight across the barrier] -> s_barrier ->
// ds_read+MFMA (setprio 1) -> s_barrier [guards buffer overwrite].
// Hazards: barrier2 ensures all waves finished reading cur before the next
// iteration's stage overwrites it; sched_barrier(0) fences keep ds_reads
// inside the barrier pair (rule #18: compiler hoists reg-only MFMA past
// inline-asm waits; rule #21 analog for ds_read sink).
// KV mode (Vt != null): cols >= 768 are the V projection, written TRANSPOSED
// into VbT [bh][hd][s].
__device__ __forceinline__ void gemm_core(const ushort* __restrict__ A, const ushort* __restrict__ B,
    const float* __restrict__ bias, const float* __restrict__ bias2,
    float* __restrict__ Cf, ushort* __restrict__ Cb, ushort* __restrict__ Vt,
    int N, int K, int m0, int n0, int relu, ushort* As, ushort* Bs) {
  const int t = threadIdx.x;
  const int lane = t & 63, wave = t >> 6;
  const int quad = lane >> 4, lrow = lane & 15;
  const int wr = (wave >> 1) * 64, wc = (wave & 1) * 64;
  const int srow = t >> 2, scol = (t & 3) * 8;
  const ushort* ag = A + (size_t)(m0 + srow) * K + scol;
  const ushort* bg = B + (size_t)(n0 + srow) * K + scol;
  ushort* asw = As + t * 8;   // linear dest: byte 16*t within buffer
  ushort* bsw = Bs + t * 8;
  f32x4 acc[4][4] = {};
  // prologue: stage k-step 0 into buffer 0
  gl2lds16(ag,                  asw);
  gl2lds16(ag + (size_t)64 * K, asw + 64 * 32);
  gl2lds16(bg,                  bsw);
  gl2lds16(bg + (size_t)64 * K, bsw + 64 * 32);
  int cur = 0;
  for (int k0 = 0; k0 < K; k0 += 32) {
    if (k0 + 32 < K) {                      // prefetch next k-step into other buf
      const int nb = (cur ^ 1) * (128 * 32);
      gl2lds16(ag + k0 + 32,                  asw + nb);
      gl2lds16(ag + k0 + 32 + (size_t)64 * K, asw + nb + 64 * 32);
      gl2lds16(bg + k0 + 32,                  bsw + nb);
      gl2lds16(bg + k0 + 32 + (size_t)64 * K, bsw + nb + 64 * 32);
      asm volatile("s_waitcnt vmcnt(4)" ::: "memory");   // cur's 4 loads done; prefetch flying
    } else {
      asm volatile("s_waitcnt vmcnt(0)" ::: "memory");
    }
    __builtin_amdgcn_s_barrier();           // all waves have cur staged
    __builtin_amdgcn_sched_barrier(0);
    const ushort* as = As + cur * (128 * 32);
    const ushort* bs = Bs + cur * (128 * 32);
    bf16x8 af[4], bfr[4];
    #pragma unroll
    for (int i = 0; i < 4; ++i) af[i] = *(const bf16x8*)&as[(wr + i * 16 + lrow) * 32 + quad * 8];
    #pragma unroll
    for (int j = 0; j < 4; ++j) bfr[j] = *(const bf16x8*)&bs[(wc + j * 16 + lrow) * 32 + quad * 8];
    __builtin_amdgcn_s_setprio(1);
    #pragma unroll
    for (int i = 0; i < 4; ++i)
      #pragma unroll
      for (int j = 0; j < 4; ++j)
        acc[i][j] = __builtin_amdgcn_mfma_f32_16x16x32_bf16(af[i], bfr[j], acc[i][j], 0, 0, 0);
    __builtin_amdgcn_s_setprio(0);
    __builtin_amdgcn_sched_barrier(0);
    __builtin_amdgcn_s_barrier();           // all done reading cur -> safe to overwrite
    __builtin_amdgcn_sched_barrier(0);
    cur ^= 1;
  }
  #pragma unroll
  for (int i = 0; i < 4; ++i) {
    #pragma unroll
    for (int j = 0; j < 4; ++j) {
      const int gcol = n0 + wc + j * 16 + lrow;
      const float bv = (bias2 && gcol >= D_) ? bias2[gcol - D_] : (bias ? bias[gcol] : 0.f);
      if (Vt && gcol >= D_) {
        const int dv = gcol - D_, hh = dv / HD_, hd = dv % HD_;
        const int row0 = m0 + wr + i * 16 + quad * 4;
        const int bb = row0 / S_, ss = row0 % S_;
        ushort4 o;
        o.x = f2bf(acc[i][j][0] + bv);
        o.y = f2bf(acc[i][j][1] + bv);
        o.z = f2bf(acc[i][j][2] + bv);
        o.w = f2bf(acc[i][j][3] + bv);
        *(ushort4*)&Vt[((size_t)(bb * NH_ + hh) * HD_ + hd) * SP_ + ss] = o;
      } else {
        #pragma unroll
        for (int r = 0; r < 4; ++r) {
          const int grow = m0 + wr + i * 16 + quad * 4 + r;
          float v = acc[i][j][r] + bv;
          if (relu) v = fmaxf(v, 0.f);
          if (Cf) Cf[(size_t)grow * N + gcol] = v;
          else    Cb[(size_t)grow * N + gcol] = f2bf(v);
        }
      }
    }
  }
}

// 1-D grid with XCD-aware swizzle. Optional second job (A2 != null) runs in
// tail blocks (folds the tiny q-proj into the embed dispatch).
__global__ __launch_bounds__(256) void k_gemm(const ushort* __restrict__ A, const ushort* __restrict__ B,
    const float* __restrict__ bias, const float* __restrict__ bias2,
    float* __restrict__ Cf, ushort* __restrict__ Cb, ushort* __restrict__ Vt,
    int N, int K, int nbx, int nm, int relu,
    const ushort* __restrict__ A2, const ushort* __restrict__ B2,
    const float* __restrict__ bias_2, ushort* __restrict__ Cb2, int N2, int K2) {
  __shared__ ushort As[2 * 128 * 32];
  __shared__ ushort Bs[2 * 128 * 32];
  const int l = blockIdx.x;
  const int base = ((nm + 7) & ~7) * nbx;
  if (l >= base) {
    gemm_core(A2, B2, bias_2, nullptr, nullptr, Cb2, nullptr, N2, K2, 0, (l - base) * 128, 0, As, Bs);
    return;
  }
  const int mb = (l >> 3) / nbx * 8 + (l & 7);
  const int nb = (l >> 3) % nbx;
  if (mb >= nm) return;
  gemm_core(A, B, bias, bias2, Cf, Cb, Vt, N, K, mb * 128, nb * 128, relu, As, Bs);
}
static inline int swz_grid(int nm, int nbx) { return ((nm + 7) & ~7) * nbx; }

// ---------------- 64x128-tile GEMM core (R9; R11 counted-vmcnt) ------------
__device__ __forceinline__ void gemm_core64(const ushort* __restrict__ A, const ushort* __restrict__ B,
    const float* __restrict__ bias, ushort* __restrict__ Cb,
    int N, int K, int m0, int n0, int relu, ushort* As, ushort* Bs) {
  const int t = threadIdx.x;
  const int lane = t & 63, wave = t >> 6;
  const int quad = lane >> 4, lrow = lane & 15;
  const int wr = (wave >> 1) * 32, wc = (wave & 1) * 64;
  const int srow = t >> 2, scol = (t & 3) * 8;
  const ushort* ag = A + (size_t)(m0 + srow) * K + scol;
  const ushort* bg = B + (size_t)(n0 + srow) * K + scol;
  ushort* asw = As + t * 8;
  ushort* bsw = Bs + t * 8;
  f32x4 acc[2][4] = {};
  gl2lds16(ag,                  asw);
  gl2lds16(bg,                  bsw);
  gl2lds16(bg + (size_t)64 * K, bsw + 64 * 32);
  int cur = 0;
  for (int k0 = 0; k0 < K; k0 += 32) {
    if (k0 + 32 < K) {
      gl2lds16(ag + k0 + 32,                  asw + (cur ^ 1) * (64 * 32));
      gl2lds16(bg + k0 + 32,                  bsw + (cur ^ 1) * (128 * 32));
      gl2lds16(bg + k0 + 32 + (size_t)64 * K, bsw + (cur ^ 1) * (128 * 32) + 64 * 32);
      asm volatile("s_waitcnt vmcnt(3)" ::: "memory");
    } else {
      asm volatile("s_waitcnt vmcnt(0)" ::: "memory");
    }
    __builtin_amdgcn_s_barrier();
    __builtin_amdgcn_sched_barrier(0);
    const ushort* as = As + cur * (64 * 32);
    const ushort* bs = Bs + cur * (128 * 32);
    bf16x8 af[2], bfr[4];
    #pragma unroll
    for (int i = 0; i < 2; ++i) af[i] = *(const bf16x8*)&as[(wr + i * 16 + lrow) * 32 + quad * 8];
    #pragma unroll
    for (int j = 0; j < 4; ++j) bfr[j] = *(const bf16x8*)&bs[(wc + j * 16 + lrow) * 32 + quad * 8];
    __builtin_amdgcn_s_setprio(1);
    #pragma unroll
    for (int i = 0; i < 2; ++i)
      #pragma unroll
      for (int j = 0; j < 4; ++j)
        acc[i][j] = __builtin_amdgcn_mfma_f32_16x16x32_bf16(af[i], bfr[j], acc[i][j], 0, 0, 0);
    __builtin_amdgcn_s_setprio(0);
    __builtin_amdgcn_sched_barrier(0);
    __builtin_amdgcn_s_barrier();
    __builtin_amdgcn_sched_barrier(0);
    cur ^= 1;
  }
  #pragma unroll
  for (int i = 0; i < 2; ++i) {
    #pragma unroll
    for (int j = 0; j < 4; ++j) {
      const int gcol = n0 + wc + j * 16 + lrow;
      const float bv = bias ? bias[gcol] : 0.f;
      #pragma unroll
      for (int r = 0; r < 4; ++r) {
        const int grow = m0 + wr + i * 16 + quad * 4 + r;
        float v = acc[i][j][r] + bv;
        if (relu) v = fmaxf(v, 0.f);
        Cb[(size_t)grow * N + gcol] = f2bf(v);
      }
    }
  }
}

__global__ __launch_bounds__(256) void k_gemm64(const ushort* __restrict__ A, const ushort* __restrict__ B,
    const float* __restrict__ bias, ushort* __restrict__ Cb,
    int N, int K, int nbx, int nm, int relu,
    const ushort* __restrict__ A2, const ushort* __restrict__ B2,
    const float* __restrict__ bias_2, ushort* __restrict__ Cb2, int N2, int K2, int nbx2) {
  __shared__ ushort As[2 * 64 * 32];
  __shared__ ushort Bs[2 * 128 * 32];
  const int l = blockIdx.x;
  const int base = ((nm + 7) & ~7) * nbx;
  if (l >= base) {
    const int l2 = l - base;
    gemm_core64(A2, B2, bias_2, Cb2, N2, K2, (l2 / nbx2) * 64, (l2 % nbx2) * 128, 0, As, Bs);
    return;
  }
  const int mb = (l >> 3) / nbx * 8 + (l & 7);
  const int nb = (l >> 3) % nbx;
  if (mb >= nm) return;
  gemm_core64(A, B, bias, Cb, N, K, mb * 64, nb * 128, relu, As, Bs);
}

// ---------------- fused attention: QK^T + softmax + PV ---------------------
// grid (NH, B), block 256. K staged to LDS; P lives in regs then LDS (union
// with K buffer); V B-frags read straight from global VbT (each elem once).
__global__ __launch_bounds__(256) void k_attn(const ushort* __restrict__ qB,
    const ushort* __restrict__ Kb, const ushort* __restrict__ VbT, ushort* __restrict__ ctx) {
  __shared__ ushort lds[GP_ * SP_];   // 50176 B; first 39936 B doubles as K stage
  ushort* Ks = lds;
  ushort* Ps = lds;
  const int h = blockIdx.x, b = blockIdx.y, t = threadIdx.x;
  const int bh = b * NH_ + h;
  const int lane = t & 63, wave = t >> 6;
  const int quad = lane >> 4, c = lane & 15;
  for (int i = t; i < 208 * 12; i += 256) {
    int r = i / 12, col = (i % 12) * 8;
    gl2lds16(Kb + ((size_t)(b * S_ + r)) * D_ + h * HD_ + col, &Ks[i * 8]);
  }
  __syncthreads();
  const float scale = 0.1020620726f;  // 1/sqrt(96)
  f32x4 p[2][13];
  #pragma unroll
  for (int rep = 0; rep < 2; ++rep) {
    const int ii = wave + rep * 4;
    if (ii >= 7) continue;
    bf16x8 af[3];
    #pragma unroll
    for (int ks = 0; ks < 3; ++ks)
      af[ks] = *(const bf16x8*)(qB + ((size_t)(ii * 16 + c)) * D_ + h * HD_ + ks * 32 + quad * 8);
    __builtin_amdgcn_s_setprio(1);
    #pragma unroll
    for (int j = 0; j < 13; ++j) {
      f32x4 a = {};
      #pragma unroll
      for (int ks = 0; ks < 3; ++ks) {
        bf16x8 bf = *(const bf16x8*)&Ks[(j * 16 + c) * HD_ + ks * 32 + quad * 8];
        a = __builtin_amdgcn_mfma_f32_16x16x32_bf16(af[ks], bf, a, 0, 0, 0);
      }
      p[rep][j] = a;
    }
    __builtin_amdgcn_s_setprio(0);
    float m[4] = {-1e30f, -1e30f, -1e30f, -1e30f};
    #pragma unroll
    for (int j = 0; j < 13; ++j)
      #pragma unroll
      for (int r = 0; r < 4; ++r) {
        float v = p[rep][j][r] * scale;
        if (j == 12 && c >= 4) v = -1e30f;   // mask padded s 196..207 (kills NaN too)
        p[rep][j][r] = v;
        m[r] = fmaxf(m[r], v);
      }
    #pragma unroll
    for (int r = 0; r < 4; ++r) {
      m[r] = fmaxf(m[r], __shfl_xor(m[r], 1));
      m[r] = fmaxf(m[r], __shfl_xor(m[r], 2));
      m[r] = fmaxf(m[r], __shfl_xor(m[r], 4));
      m[r] = fmaxf(m[r], __shfl_xor(m[r], 8));
    }
    float lsum[4] = {0.f, 0.f, 0.f, 0.f};
    #pragma unroll
    for (int j = 0; j < 13; ++j)
      #pragma unroll
      for (int r = 0; r < 4; ++r) {
        float e = __expf(p[rep][j][r] - m[r]);
        p[rep][j][r] = e; lsum[r] += e;
      }
    #pragma unroll
    for (int r = 0; r < 4; ++r) {
      lsum[r] += __shfl_xor(lsum[r], 1);
      lsum[r] += __shfl_xor(lsum[r], 2);
      lsum[r] += __shfl_xor(lsum[r], 4);
      lsum[r] += __shfl_xor(lsum[r], 8);
      lsum[r] = 1.f / lsum[r];
    }
    #pragma unroll
    for (int j = 0; j < 13; ++j)
      #pragma unroll
      for (int r = 0; r < 4; ++r)
        p[rep][j][r] *= lsum[r];
  }
  __syncthreads();   // everyone done reading Ks -> safe to overwrite with Ps
  #pragma unroll
  for (int rep = 0; rep < 2; ++rep) {
    const int ii = wave + rep * 4;
    if (ii >= 7) continue;
    #pragma unroll
    for (int r = 0; r < 4; ++r) {
      const int g = ii * 16 + quad * 4 + r;
      #pragma unroll
      for (int j = 0; j < 13; ++j)
        Ps[g * SP_ + j * 16 + c] = f2bf(p[rep][j][r]);
      Ps[g * SP_ + 208 + c] = 0;   // pad s 208..223
    }
  }
  __syncthreads();
  #pragma unroll
  for (int rep = 0; rep < 2; ++rep) {
    const int ii = wave + rep * 4;
    if (ii >= 7) continue;
    bf16x8 af[7];
    #pragma unroll
    for (int k = 0; k < 7; ++k)
      af[k] = *(const bf16x8*)&Ps[(ii * 16 + c) * SP_ + k * 32 + quad * 8];
    #pragma unroll
    for (int j = 0; j < 6; ++j) {
      f32x4 acc = {};
      __builtin_amdgcn_s_setprio(1);
      #pragma unroll
      for (int k = 0; k < 7; ++k) {
        bf16x8 bf = *(const bf16x8*)(VbT + ((size_t)bh * HD_ + j * 16 + c) * SP_ + k * 32 + quad * 8);
        acc = __builtin_amdgcn_mfma_f32_16x16x32_bf16(af[k], bf, acc, 0, 0, 0);
      }
      __builtin_amdgcn_s_setprio(0);
      #pragma unroll
      for (int r = 0; r < 4; ++r) {
        const int g = ii * 16 + quad * 4 + r;
        if (g < G_)
          ctx[((size_t)(b * G_ + g)) * D_ + h * HD_ + j * 16 + c] = f2bf(acc[r]);
      }
    }
  }
}

// ---------------- residual + LayerNorm (add-input bf16) --------------------
// transb: bf16 out written transposed as [g][b][768] (for the head's A-operand)
__global__ __launch_bounds__(256) void k_lnres(const float* __restrict__ resid, int resid_mod,
    const ushort* __restrict__ addB, const float* __restrict__ gamma, const float* __restrict__ beta,
    float* __restrict__ outf, ushort* __restrict__ outb, int transb) {
  const int row = blockIdx.x, t = threadIdx.x;
  __shared__ float r1[256], r2[256];
  const float* rrow = resid + (size_t)(resid_mod ? (row % G_) : row) * D_;
  const ushort* arow = addB + (size_t)row * D_;
  float y[3]; float s = 0.f, sq = 0.f;
  #pragma unroll
  for (int i = 0; i < 3; ++i) {
    int d = t + i * 256;
    float v = rrow[d] + bf2f(arow[d]);
    y[i] = v; s += v; sq += v * v;
  }
  r1[t] = s; r2[t] = sq; __syncthreads();
  for (int o = 128; o > 0; o >>= 1) { if (t < o) { r1[t] += r1[t + o]; r2[t] += r2[t + o]; } __syncthreads(); }
  const float mean = r1[0] * (1.f / D_);
  const float var  = r2[0] * (1.f / D_) - mean * mean;
  const float w = rsqrtf(var + 1e-5f);
  const size_t orow = transb ? ((size_t)(row % G_) * B_ + row / G_) : (size_t)row;
  #pragma unroll
  for (int i = 0; i < 3; ++i) {
    int d = t + i * 256;
    float v = (y[i] - mean) * w * gamma[d] + beta[d];
    if (outf) outf[(size_t)row * D_ + d] = v;
    if (outb) outb[orow * D_ + d] = f2bf(v);
  }
}

// ---------------- grouped head via MFMA, LDS-free, coalesced ---------------
// grid (G, 7), block 256. hT layout [g][64][768]: a wave's 64 lanes read 16
// full 64B lines per frag load (quad k-offsets land in the same line).
__global__ __launch_bounds__(256) void k_head4(const ushort* __restrict__ hT,
    const ushort* __restrict__ dupT, const float* __restrict__ dup_bias, float* __restrict__ out) {
  const int g = blockIdx.x, j = blockIdx.y, t = threadIdx.x;
  const int lane = t & 63, wave = t >> 6;
  const int quad = lane >> 4, c = lane & 15;
  const ushort* ap = hT + ((size_t)g * B_ + wave * 16 + c) * D_;
  const ushort* bp = dupT + ((size_t)g * FP_ + j * 16 + c) * D_;
  f32x4 acc = {};
  #pragma unroll 8
  for (int k0 = 0; k0 < D_; k0 += 32) {
    bf16x8 af = *(const bf16x8*)(ap + k0 + quad * 8);
    bf16x8 bf = *(const bf16x8*)(bp + k0 + quad * 8);
    acc = __builtin_amdgcn_mfma_f32_16x16x32_bf16(af, bf, acc, 0, 0, 0);
  }
  const int f = j * 16 + c;
  if (f >= DF_) return;
  const int n = g * DF_ + f;
  if (n >= NC_) return;
  const float bv = dup_bias[n];
  #pragma unroll
  for (int r = 0; r < 4; ++r) {
    const int b = wave * 16 + quad * 4 + r;
    out[(size_t)b * NC_ + n] = acc[r] + bv;
  }
}

// ---------------------------------------------------------------------------
// workspace layout (bytes)
// region 0 timeline: aemb (until embed GEMM) -> VbT (KV epilogue .. attn) ->
//                    ffB/ffoB (FFN)
// ---------------------------------------------------------------------------
static constexpr size_t OFF_AEMB  = 0;          // bf16 [12544,2048] = 51,380,224
static constexpr size_t OFF_VBT   = 0;          // bf16 [512,96,224]  = 22,020,096
static constexpr size_t OFF_FF    = 0;          // bf16 [6400,2048] = 26,214,400
static constexpr size_t OFF_FFO   = 26214400;   // bf16 [6400,768]  = 9,830,400 (end 36,044,800)
static constexpr size_t OFF_WEMB  = 51380224;   // bf16 3,145,728
static constexpr size_t OFF_MEM   = 54525952;   // bf16 [12544,768] = 19,267,584
static constexpr size_t OFF_WK    = 73793536;   // 1,179,648   (wk|wv contiguous = fused 1536x768)
static constexpr size_t OFF_WV    = 74973184;   // 1,179,648
static constexpr size_t OFF_WO    = 76152832;   // 1,179,648
static constexpr size_t OFF_W1    = 77332480;   // 3,145,728
static constexpr size_t OFF_W2    = 80478208;   // 3,145,728
static constexpr size_t OFF_DUP   = 83623936;   // bf16 [100,112,768] = 17,203,200
static constexpr size_t OFF_KB    = 100827136;  // bf16 [12544,768] = 19,267,584
static constexpr size_t OFF_TGT   = 139362304;  // f32 [100,768] = 307,200
static constexpr size_t OFF_TGTB  = 139669504;  // bf16 [128,768] = 196,608
static constexpr size_t OFF_Q     = 139866112;  // bf16 [128,768] = 196,608
static constexpr size_t OFF_CTX   = 140068864;  // bf16 9,830,400 (also wqB early: dead before attn)
static constexpr size_t OFF_WQ    = OFF_CTX;    // bf16 [768,768] = 1,179,648 (consumed before ctx written)
static constexpr size_t OFF_CTXO  = 149899264;  // bf16 [6400,768] = 9,830,400
static constexpr size_t OFF_TGT2F = 169560064;  // f32 19,660,800
static constexpr size_t OFF_TGT2B = 189220864;  // bf16 9,830,400
static constexpr size_t OFF_HB    = 199051264;  // bf16 [100,64,768] = 9,830,400 (end 208,881,664)

extern "C" void kernel_launch(void* const* d_in, const int* in_sizes, int n_in,
                              void* d_out, int out_size, void* d_ws, size_t ws_size,
                              hipStream_t stream) {
  const float* x           = (const float*)d_in[0];
  const float* w_embed     = (const float*)d_in[1];
  const float* b_embed     = (const float*)d_in[2];
  const float* query_embed = (const float*)d_in[3];
  const float* wq          = (const float*)d_in[4];
  const float* bq          = (const float*)d_in[5];
  const float* wk          = (const float*)d_in[6];
  const float* bk          = (const float*)d_in[7];
  const float* wv          = (const float*)d_in[8];
  const float* bv          = (const float*)d_in[9];
  const float* wo          = (const float*)d_in[10];
  const float* bo          = (const float*)d_in[11];
  const float* g1          = (const float*)d_in[12];
  const float* be1         = (const float*)d_in[13];
  const float* g2          = (const float*)d_in[14];
  const float* be2         = (const float*)d_in[15];
  const float* g3          = (const float*)d_in[16];
  const float* be3         = (const float*)d_in[17];
  const float* w1          = (const float*)d_in[18];
  const float* bl1         = (const float*)d_in[19];
  const float* w2          = (const float*)d_in[20];
  const float* bl2         = (const float*)d_in[21];
  const float* dup_pool    = (const float*)d_in[22];
  const float* dup_bias    = (const float*)d_in[23];
  float* out = (float*)d_out;
  char* ws = (char*)d_ws;

  ushort* aemb  = (ushort*)(ws + OFF_AEMB);
  ushort* wembB = (ushort*)(ws + OFF_WEMB);
  ushort* memB  = (ushort*)(ws + OFF_MEM);
  ushort* wkvB  = (ushort*)(ws + OFF_WK);    // fused [1536][768]
  ushort* wkB   = (ushort*)(ws + OFF_WK);
  ushort* wvB   = (ushort*)(ws + OFF_WV);
  ushort* woB   = (ushort*)(ws + OFF_WO);
  ushort* w1B   = (ushort*)(ws + OFF_W1);
  ushort* w2B   = (ushort*)(ws + OFF_W2);
  ushort* wqB   = (ushort*)(ws + OFF_WQ);
  ushort* dupT  = (ushort*)(ws + OFF_DUP);
  ushort* Kb    = (ushort*)(ws + OFF_KB);
  float*  tgtF  = (float*)(ws + OFF_TGT);
  ushort* tgtB  = (ushort*)(ws + OFF_TGTB);
  ushort* qB    = (ushort*)(ws + OFF_Q);
  ushort* VbT   = (ushort*)(ws + OFF_VBT);
  ushort* ctxB  = (ushort*)(ws + OFF_CTX);
  ushort* ctxoB = (ushort*)(ws + OFF_CTXO);
  float*  tgt2F = (float*)(ws + OFF_TGT2F);
  ushort* tgt2B = (ushort*)(ws + OFF_TGT2B);
  ushort* ffB   = (ushort*)(ws + OFF_FF);
  ushort* ffoB  = (ushort*)(ws + OFF_FFO);
  ushort* hT    = (ushort*)(ws + OFF_HB);

  // 1. fused prep: dup-transpose, x-transpose, weight converts, tgt LN
  PrepArgs pa;
  pa.x = x; pa.aemb = aemb;
  pa.dup = dup_pool; pa.dupT = dupT;
  pa.csrc[0] = w_embed; pa.cdst[0] = wembB; pa.cn4[0] = D_ * CIN_ / 8;
  pa.csrc[1] = wk;      pa.cdst[1] = wkB;   pa.cn4[1] = D_ * D_ / 8;
  pa.csrc[2] = wv;      pa.cdst[2] = wvB;   pa.cn4[2] = D_ * D_ / 8;
  pa.csrc[3] = wo;      pa.cdst[3] = woB;   pa.cn4[3] = D_ * D_ / 8;
  pa.csrc[4] = w1;      pa.cdst[4] = w1B;   pa.cn4[4] = FF_ * D_ / 8;
  pa.csrc[5] = w2;      pa.cdst[5] = w2B;   pa.cn4[5] = D_ * FF_ / 8;
  pa.csrc[6] = wq;      pa.cdst[6] = wqB;   pa.cn4[6] = D_ * D_ / 8;
  pa.ctotal = pa.cn4[0] + pa.cn4[1] + pa.cn4[2] + pa.cn4[3] + pa.cn4[4] + pa.cn4[5] + pa.cn4[6];
  pa.qe = query_embed; pa.g1 = g1; pa.be1 = be1; pa.tgt = tgtF; pa.tgtB = tgtB;
  k_prep<<<DT_BLKS + XP_BLKS + CV_BLKS + TG_BLKS, 256, 0, stream>>>(pa);

  // 2. embed GEMM + relu -> mem bf16 (64-row tiles: 1200 blocks = 4.7/CU);
  //    tail 12 blocks: qB = tgtB@wq^T + bq
  k_gemm64<<<swz_grid(196, 6) + 12, 256, 0, stream>>>(aemb, wembB, b_embed, memB,
                                                      D_, CIN_, 6, 196, 1,
                                                      tgtB, wqB, bq, qB, D_, D_, 6);

  // 3. fused K|V projection: K -> Kb [12544,768], V -> VbT [512][96][224] transposed
  k_gemm<<<swz_grid(98, 12), 256, 0, stream>>>(memB, wkvB, bk, bv, nullptr, Kb, VbT,
                                               D_, D_, 12, 98, 0,
                                               nullptr, nullptr, nullptr, nullptr, 0, 0);

  // 4. fused attention (QK^T + softmax + PV)
  k_attn<<<dim3(NH_, B_), 256, 0, stream>>>(qB, Kb, VbT, ctxB);

  // 5. ctx @ wo^T + bo -> bf16 [6400, 768] (64-row tiles: 624 blocks)
  k_gemm64<<<swz_grid(100, 6), 256, 0, stream>>>(ctxB, woB, bo, ctxoB,
                                                 D_, D_, 6, 100, 0,
                                                 nullptr, nullptr, nullptr, nullptr, 0, 0, 1);

  // 6. tgt2 = LN(tgt + ctxo)
  k_lnres<<<BG_, 256, 0, stream>>>(tgtF, 1, ctxoB, g2, be2, tgt2F, tgt2B, 0);

  // 7-8. FFN (FFN1 stays 128x128: 896 blocks = 3.5/CU; FFN2 64-row: 624 blocks)
  k_gemm<<<swz_grid(50, 16), 256, 0, stream>>>(tgt2B, w1B, bl1, nullptr, nullptr, ffB, nullptr,
                                               FF_, D_, 16, 50, 1,
                                               nullptr, nullptr, nullptr, nullptr, 0, 0);
  k_gemm64<<<swz_grid(100, 6), 256, 0, stream>>>(ffB, w2B, bl2, ffoB,
                                                 D_, FF_, 6, 100, 0,
                                                 nullptr, nullptr, nullptr, nullptr, 0, 0, 1);

  // 9. h = LN(tgt2 + ffo) -> bf16 transposed [g][64][768]
  k_lnres<<<BG_, 256, 0, stream>>>(tgt2F, 0, ffoB, g3, be3, nullptr, hT, 1);

  // 10. grouped head -> logits fp32 [64, 9605] via MFMA (coalesced, LDS-free)
  k_head4<<<dim3(G_, 7), 256, 0, stream>>>(hT, dupT, dup_bias, out);
}

// Round 5
// 556.617 us; speedup vs baseline: 1.0087x; 1.0087x over previous
//
#include <hip/hip_runtime.h>
#include <hip/hip_bf16.h>

// ---------------------------------------------------------------------------
// MLDecoder classification head, MI355X bf16-MFMA implementation.
// B=64, C_IN=2048, H=W=14 (S=196), D=768, FF=2048, G=100, NC=9605, NH=8, HD=96
// ---------------------------------------------------------------------------

#define B_    64
#define CIN_  2048
#define S_    196
#define D_    768
#define FF_   2048
#define G_    100
#define NC_   9605
#define NH_   8
#define HD_   96
#define DF_   97
#define FP_   112          // DF_ padded to 16
#define GP_   112          // G padded to 16
#define SP_   224          // S padded to 32 (7 K-steps) for P / V^T
#define BS_   (B_ * S_)   // 12544
#define BG_   (B_ * G_)   // 6400

typedef __bf16 bf16x8 __attribute__((ext_vector_type(8)));
typedef float  f32x4  __attribute__((ext_vector_type(4)));
typedef ushort us8    __attribute__((ext_vector_type(8)));

__device__ __forceinline__ float bf2f(ushort u) {
  union { unsigned int i; float f; } v; v.i = ((unsigned int)u) << 16; return v.f;
}
__device__ __forceinline__ ushort f2bf(float f) {
  __hip_bfloat16 h = __float2bfloat16(f);
  return *reinterpret_cast<ushort*>(&h);
}

// async global->LDS, 16 bytes per lane. LDS target must be wave-uniform base
// + lane*16 (our staging layouts satisfy this: lds byte offset == 16*i, i linear in t).
__device__ __forceinline__ void gl2lds16(const ushort* g, ushort* l) {
  __builtin_amdgcn_global_load_lds((const __attribute__((address_space(1))) unsigned int*)g,
                                   (__attribute__((address_space(3))) unsigned int*)l, 16, 0, 0);
}

// ---------------------------------------------------------------------------
// k_prep (R12: SPLIT): only what the embed GEMM needs — x-transpose,
// wemb/wq converts, tgt LN. dupT + wk/wv/wo/w1/w2 converts moved into the
// embed dispatch (co-scheduled with its idle BW — embed ran at 9% HBM).
// xpose c-chunk 64 -> 32: LDS 28.6 -> 15.7 KB doubles blocks/CU (k_prep was
// 2.0 TB/s at 45% occupancy, 3% VALU: concurrency-starved, not BW-bound).
// ---------------------------------------------------------------------------
#define XP_BLKS  4096   // xpose: (b, c-chunk of 32), full s
#define CVP_BLKS 256    // cvt: wemb + wq, grid-stride, 8-float units
#define TG_BLKS  128    // tgt LN rows (padded)

struct PrepArgs {
  const float* x;   ushort* aemb;
  const float* csrc[2]; ushort* cdst[2]; int cn4[2]; int ctotal;  // 8-float units
  const float* qe; const float* g1; const float* be1;
  float* tgt; ushort* tgtB;
};

__global__ __launch_bounds__(256) void k_prep(PrepArgs pa) {
  __shared__ __align__(16) char smem[196 * 40 * 2];   // 15,680 B
  int jid = blockIdx.x;
  const int t = threadIdx.x;

  if (jid < XP_BLKS) {
    // x [B][C][S] f32 -> aemb [(b,s)][C] bf16. Per block: one b, 32 c, all s.
    // LDS tile [196 s][40 c] bf16 (row 80 B, 16B-aligned). Phase 1: wave =
    // 8 j x 8 cq -> 8 rows x 128 B coalesced reads; ushort4 LDS writes ~2-way.
    // Phase 2: us8 reads + 64 B contiguous global stores (4 lanes/row).
    ushort* xs = (ushort*)smem;
    const int b = jid >> 6, cbase = (jid & 63) * 32;
    const float* xb = pa.x + ((size_t)b * CIN_ + cbase) * S_;
    #pragma unroll
    for (int it = 0; it < 2; ++it) {
      const int u = it * 256 + t;
      if (u < 392) {                       // 49 s-quads x 8 c-quads
        const int j = u >> 3, cq = u & 7;
        const int s = 4 * j;
        float4 a[4];
        #pragma unroll
        for (int r = 0; r < 4; ++r)
          a[r] = *(const float4*)(xb + (size_t)(cq * 4 + r) * S_ + s);
        #pragma unroll
        for (int r = 0; r < 4; ++r) {
          ushort4 o;
          o.x = f2bf(((const float*)&a[0])[r]);
          o.y = f2bf(((const float*)&a[1])[r]);
          o.z = f2bf(((const float*)&a[2])[r]);
          o.w = f2bf(((const float*)&a[3])[r]);
          *(ushort4*)&xs[(s + r) * 40 + cq * 4] = o;
        }
      }
    }
    __syncthreads();
    const int sl = t >> 2, oct = t & 3;    // 4 lanes -> 64 B contiguous store
    #pragma unroll
    for (int sr = 0; sr < 4; ++sr) {
      const int s = sr * 64 + sl;
      if (s < S_) {
        us8 v = *(const us8*)&xs[s * 40 + oct * 8];
        *(us8*)&pa.aemb[((size_t)(b * S_ + s)) * CIN_ + cbase + oct * 8] = v;
      }
    }
    return;
  }
  jid -= XP_BLKS;

  if (jid < CVP_BLKS) {
    // wemb + wq fp32 -> bf16, 8 floats per unit.
    int i = jid * 256 + t;
    const int stride = CVP_BLKS * 256;
    for (; i < pa.ctotal; i += stride) {
      int seg = 0, off = i;
      while (off >= pa.cn4[seg]) { off -= pa.cn4[seg]; ++seg; }
      const float4* sp = (const float4*)pa.csrc[seg];
      float4 v0 = sp[2 * off], v1 = sp[2 * off + 1];
      us8 o;
      o[0] = f2bf(v0.x); o[1] = f2bf(v0.y); o[2] = f2bf(v0.z); o[3] = f2bf(v0.w);
      o[4] = f2bf(v1.x); o[5] = f2bf(v1.y); o[6] = f2bf(v1.z); o[7] = f2bf(v1.w);
      ((us8*)pa.cdst[seg])[off] = o;
    }
    return;
  }
  jid -= CVP_BLKS;

  // tgt = LN(2*query_embed)*g1 + be1 -> fp32 [100,768] + bf16 [128,768] (pad 0)
  float* r1 = (float*)smem;
  float* r2 = r1 + 256;
  const int g = jid;
  if (g >= G_) {
    for (int d = t; d < D_; d += 256) pa.tgtB[(size_t)g * D_ + d] = 0;
    return;
  }
  float y[3]; float s = 0.f, sq = 0.f;
  const float* row = pa.qe + (size_t)g * D_;
  #pragma unroll
  for (int i = 0; i < 3; ++i) { float v = 2.f * row[t + i * 256]; y[i] = v; s += v; sq += v * v; }
  r1[t] = s; r2[t] = sq; __syncthreads();
  for (int o = 128; o > 0; o >>= 1) { if (t < o) { r1[t] += r1[t + o]; r2[t] += r2[t + o]; } __syncthreads(); }
  const float mean = r1[0] * (1.f / D_);
  const float var  = r2[0] * (1.f / D_) - mean * mean;
  const float w = rsqrtf(var + 1e-5f);
  #pragma unroll
  for (int i = 0; i < 3; ++i) {
    int d = t + i * 256;
    float v = (y[i] - mean) * w * pa.g1[d] + pa.be1[d];
    pa.tgt[(size_t)g * D_ + d] = v;
    pa.tgtB[(size_t)g * D_ + d] = f2bf(v);
  }
}

// ---------------- bf16 MFMA GEMM core: C[M,N] = A[M,K]*B[N,K]^T + bias -----
// 128x128 tile, BK=32, counted-vmcnt two-barrier k-loop (R11).
// KV mode (Vt != null): cols >= 768 are the V projection, written TRANSPOSED
// into VbT [bh][hd][s].
__device__ __forceinline__ void gemm_core(const ushort* __restrict__ A, const ushort* __restrict__ B,
    const float* __restrict__ bias, const float* __restrict__ bias2,
    float* __restrict__ Cf, ushort* __restrict__ Cb, ushort* __restrict__ Vt,
    int N, int K, int m0, int n0, int relu, ushort* As, ushort* Bs) {
  const int t = threadIdx.x;
  const int lane = t & 63, wave = t >> 6;
  const int quad = lane >> 4, lrow = lane & 15;
  const int wr = (wave >> 1) * 64, wc = (wave & 1) * 64;
  const int srow = t >> 2, scol = (t & 3) * 8;
  const ushort* ag = A + (size_t)(m0 + srow) * K + scol;
  const ushort* bg = B + (size_t)(n0 + srow) * K + scol;
  ushort* asw = As + t * 8;   // linear dest: byte 16*t within buffer
  ushort* bsw = Bs + t * 8;
  f32x4 acc[4][4] = {};
  gl2lds16(ag,                  asw);
  gl2lds16(ag + (size_t)64 * K, asw + 64 * 32);
  gl2lds16(bg,                  bsw);
  gl2lds16(bg + (size_t)64 * K, bsw + 64 * 32);
  int cur = 0;
  for (int k0 = 0; k0 < K; k0 += 32) {
    if (k0 + 32 < K) {                      // prefetch next k-step into other buf
      const int nb = (cur ^ 1) * (128 * 32);
      gl2lds16(ag + k0 + 32,                  asw + nb);
      gl2lds16(ag + k0 + 32 + (size_t)64 * K, asw + nb + 64 * 32);
      gl2lds16(bg + k0 + 32,                  bsw + nb);
      gl2lds16(bg + k0 + 32 + (size_t)64 * K, bsw + nb + 64 * 32);
      asm volatile("s_waitcnt vmcnt(4)" ::: "memory");   // cur staged; prefetch flying
    } else {
      asm volatile("s_waitcnt vmcnt(0)" ::: "memory");
    }
    __builtin_amdgcn_s_barrier();
    __builtin_amdgcn_sched_barrier(0);
    const ushort* as = As + cur * (128 * 32);
    const ushort* bs = Bs + cur * (128 * 32);
    bf16x8 af[4], bfr[4];
    #pragma unroll
    for (int i = 0; i < 4; ++i) af[i] = *(const bf16x8*)&as[(wr + i * 16 + lrow) * 32 + quad * 8];
    #pragma unroll
    for (int j = 0; j < 4; ++j) bfr[j] = *(const bf16x8*)&bs[(wc + j * 16 + lrow) * 32 + quad * 8];
    __builtin_amdgcn_s_setprio(1);
    #pragma unroll
    for (int i = 0; i < 4; ++i)
      #pragma unroll
      for (int j = 0; j < 4; ++j)
        acc[i][j] = __builtin_amdgcn_mfma_f32_16x16x32_bf16(af[i], bfr[j], acc[i][j], 0, 0, 0);
    __builtin_amdgcn_s_setprio(0);
    __builtin_amdgcn_sched_barrier(0);
    __builtin_amdgcn_s_barrier();           // all done reading cur -> safe to overwrite
    __builtin_amdgcn_sched_barrier(0);
    cur ^= 1;
  }
  #pragma unroll
  for (int i = 0; i < 4; ++i) {
    #pragma unroll
    for (int j = 0; j < 4; ++j) {
      const int gcol = n0 + wc + j * 16 + lrow;
      const float bv = (bias2 && gcol >= D_) ? bias2[gcol - D_] : (bias ? bias[gcol] : 0.f);
      if (Vt && gcol >= D_) {
        const int dv = gcol - D_, hh = dv / HD_, hd = dv % HD_;
        const int row0 = m0 + wr + i * 16 + quad * 4;
        const int bb = row0 / S_, ss = row0 % S_;
        ushort4 o;
        o.x = f2bf(acc[i][j][0] + bv);
        o.y = f2bf(acc[i][j][1] + bv);
        o.z = f2bf(acc[i][j][2] + bv);
        o.w = f2bf(acc[i][j][3] + bv);
        *(ushort4*)&Vt[((size_t)(bb * NH_ + hh) * HD_ + hd) * SP_ + ss] = o;
      } else {
        #pragma unroll
        for (int r = 0; r < 4; ++r) {
          const int grow = m0 + wr + i * 16 + quad * 4 + r;
          float v = acc[i][j][r] + bv;
          if (relu) v = fmaxf(v, 0.f);
          if (Cf) Cf[(size_t)grow * N + gcol] = v;
          else    Cb[(size_t)grow * N + gcol] = f2bf(v);
        }
      }
    }
  }
}

__global__ __launch_bounds__(256) void k_gemm(const ushort* __restrict__ A, const ushort* __restrict__ B,
    const float* __restrict__ bias, const float* __restrict__ bias2,
    float* __restrict__ Cf, ushort* __restrict__ Cb, ushort* __restrict__ Vt,
    int N, int K, int nbx, int nm, int relu) {
  __shared__ ushort As[2 * 128 * 32];
  __shared__ ushort Bs[2 * 128 * 32];
  const int l = blockIdx.x;
  const int mb = (l >> 3) / nbx * 8 + (l & 7);
  const int nb = (l >> 3) % nbx;
  if (mb >= nm) return;
  gemm_core(A, B, bias, bias2, Cf, Cb, Vt, N, K, mb * 128, nb * 128, relu, As, Bs);
}
static inline int swz_grid(int nm, int nbx) { return ((nm + 7) & ~7) * nbx; }

// ---------------- 64x128-tile GEMM core (R9/R11) ---------------------------
__device__ __forceinline__ void gemm_core64(const ushort* __restrict__ A, const ushort* __restrict__ B,
    const float* __restrict__ bias, ushort* __restrict__ Cb,
    int N, int K, int m0, int n0, int relu, ushort* As, ushort* Bs) {
  const int t = threadIdx.x;
  const int lane = t & 63, wave = t >> 6;
  const int quad = lane >> 4, lrow = lane & 15;
  const int wr = (wave >> 1) * 32, wc = (wave & 1) * 64;
  const int srow = t >> 2, scol = (t & 3) * 8;
  const ushort* ag = A + (size_t)(m0 + srow) * K + scol;
  const ushort* bg = B + (size_t)(n0 + srow) * K + scol;
  ushort* asw = As + t * 8;
  ushort* bsw = Bs + t * 8;
  f32x4 acc[2][4] = {};
  gl2lds16(ag,                  asw);
  gl2lds16(bg,                  bsw);
  gl2lds16(bg + (size_t)64 * K, bsw + 64 * 32);
  int cur = 0;
  for (int k0 = 0; k0 < K; k0 += 32) {
    if (k0 + 32 < K) {
      gl2lds16(ag + k0 + 32,                  asw + (cur ^ 1) * (64 * 32));
      gl2lds16(bg + k0 + 32,                  bsw + (cur ^ 1) * (128 * 32));
      gl2lds16(bg + k0 + 32 + (size_t)64 * K, bsw + (cur ^ 1) * (128 * 32) + 64 * 32);
      asm volatile("s_waitcnt vmcnt(3)" ::: "memory");
    } else {
      asm volatile("s_waitcnt vmcnt(0)" ::: "memory");
    }
    __builtin_amdgcn_s_barrier();
    __builtin_amdgcn_sched_barrier(0);
    const ushort* as = As + cur * (64 * 32);
    const ushort* bs = Bs + cur * (128 * 32);
    bf16x8 af[2], bfr[4];
    #pragma unroll
    for (int i = 0; i < 2; ++i) af[i] = *(const bf16x8*)&as[(wr + i * 16 + lrow) * 32 + quad * 8];
    #pragma unroll
    for (int j = 0; j < 4; ++j) bfr[j] = *(const bf16x8*)&bs[(wc + j * 16 + lrow) * 32 + quad * 8];
    __builtin_amdgcn_s_setprio(1);
    #pragma unroll
    for (int i = 0; i < 2; ++i)
      #pragma unroll
      for (int j = 0; j < 4; ++j)
        acc[i][j] = __builtin_amdgcn_mfma_f32_16x16x32_bf16(af[i], bfr[j], acc[i][j], 0, 0, 0);
    __builtin_amdgcn_s_setprio(0);
    __builtin_amdgcn_sched_barrier(0);
    __builtin_amdgcn_s_barrier();
    __builtin_amdgcn_sched_barrier(0);
    cur ^= 1;
  }
  #pragma unroll
  for (int i = 0; i < 2; ++i) {
    #pragma unroll
    for (int j = 0; j < 4; ++j) {
      const int gcol = n0 + wc + j * 16 + lrow;
      const float bv = bias ? bias[gcol] : 0.f;
      #pragma unroll
      for (int r = 0; r < 4; ++r) {
        const int grow = m0 + wr + i * 16 + quad * 4 + r;
        float v = acc[i][j][r] + bv;
        if (relu) v = fmaxf(v, 0.f);
        Cb[(size_t)grow * N + gcol] = f2bf(v);
      }
    }
  }
}

__global__ __launch_bounds__(256) void k_gemm64(const ushort* __restrict__ A, const ushort* __restrict__ B,
    const float* __restrict__ bias, ushort* __restrict__ Cb,
    int N, int K, int nbx, int nm, int relu) {
  __shared__ ushort As[2 * 64 * 32];
  __shared__ ushort Bs[2 * 128 * 32];
  const int l = blockIdx.x;
  const int mb = (l >> 3) / nbx * 8 + (l & 7);
  const int nb = (l >> 3) % nbx;
  if (mb >= nm) return;
  gemm_core64(A, B, bias, Cb, N, K, mb * 64, nb * 128, relu, As, Bs);
}

// ---------------- embed dispatch (R12): dupT + embed GEMM + q-proj + cvt ---
// dupT blocks FIRST (long-lived, start early, co-resident with GEMM blocks
// using the embed GEMM's idle HBM/CU slack); then 1200 embed-GEMM blocks
// (XCD-swizzled); then the tiny q-proj; then grid-stride weight converts.
#define DT2_BLKS 400
#define EG_BLKS  1200      // swz_grid(196, 6)
#define QP_BLKS  12
#define CV2_BLKS 256

struct EmbArgs {
  const ushort* aemb; const ushort* wembB; const float* b_embed; ushort* memB;
  const ushort* tgtB; const ushort* wqB;   const float* bq;      ushort* qB;
  const float* dup; ushort* dupT;
  const float* csrc[5]; ushort* cdst[5]; int cn4[5]; int ctotal;  // 8-float units
};

__global__ __launch_bounds__(256) void k_embed(EmbArgs ea) {
  __shared__ ushort As[2 * 64 * 32];
  __shared__ ushort Bs[2 * 128 * 32];
  int l = blockIdx.x;
  const int t = threadIdx.x;

  if (l < DT2_BLKS) {
    // dup_pool [g][d][f=97] -> dupT [g][f=112][d] bf16, f zero-padded.
    float (*tile)[33] = (float (*)[33])As;   // 4356 B, fits in As
    const int g = l >> 2, dchunk = l & 3;
    const int tx = t & 31, ty = t >> 5;
    for (int di = 0; di < 6; ++di) {
      const int d0 = dchunk * 192 + di * 32;
      for (int f0 = 0; f0 < 128; f0 += 32) {
        #pragma unroll
        for (int r = 0; r < 32; r += 8) {
          int d = d0 + ty + r, f = f0 + tx;
          tile[ty + r][tx] = (f < DF_) ? ea.dup[(size_t)g * D_ * DF_ + (size_t)d * DF_ + f] : 0.f;
        }
        __syncthreads();
        #pragma unroll
        for (int r = 0; r < 32; r += 8) {
          int f = f0 + ty + r, d = d0 + tx;
          if (f < FP_) ea.dupT[((size_t)g * FP_ + f) * D_ + d] = f2bf(tile[tx][ty + r]);
        }
        __syncthreads();
      }
    }
    return;
  }
  l -= DT2_BLKS;

  if (l < EG_BLKS) {
    const int mb = (l >> 3) / 6 * 8 + (l & 7);
    const int nb = (l >> 3) % 6;
    if (mb >= 196) return;
    gemm_core64(ea.aemb, ea.wembB, ea.b_embed, ea.memB, D_, CIN_, mb * 64, nb * 128, 1, As, Bs);
    return;
  }
  l -= EG_BLKS;

  if (l < QP_BLKS) {
    // qB[128][768] = tgtB @ wq^T + bq
    gemm_core64(ea.tgtB, ea.wqB, ea.bq, ea.qB, D_, D_, (l / 6) * 64, (l % 6) * 128, 0, As, Bs);
    return;
  }
  l -= QP_BLKS;

  // wk/wv/wo/w1/w2 fp32 -> bf16, grid-stride
  int i = l * 256 + t;
  const int stride = CV2_BLKS * 256;
  for (; i < ea.ctotal; i += stride) {
    int seg = 0, off = i;
    while (off >= ea.cn4[seg]) { off -= ea.cn4[seg]; ++seg; }
    const float4* sp = (const float4*)ea.csrc[seg];
    float4 v0 = sp[2 * off], v1 = sp[2 * off + 1];
    us8 o;
    o[0] = f2bf(v0.x); o[1] = f2bf(v0.y); o[2] = f2bf(v0.z); o[3] = f2bf(v0.w);
    o[4] = f2bf(v1.x); o[5] = f2bf(v1.y); o[6] = f2bf(v1.z); o[7] = f2bf(v1.w);
    ((us8*)ea.cdst[seg])[off] = o;
  }
}

// ---------------- fused attention: QK^T + softmax + PV ---------------------
__global__ __launch_bounds__(256) void k_attn(const ushort* __restrict__ qB,
    const ushort* __restrict__ Kb, const ushort* __restrict__ VbT, ushort* __restrict__ ctx) {
  __shared__ ushort lds[GP_ * SP_];   // 50176 B; first 39936 B doubles as K stage
  ushort* Ks = lds;
  ushort* Ps = lds;
  const int h = blockIdx.x, b = blockIdx.y, t = threadIdx.x;
  const int bh = b * NH_ + h;
  const int lane = t & 63, wave = t >> 6;
  const int quad = lane >> 4, c = lane & 15;
  for (int i = t; i < 208 * 12; i += 256) {
    int r = i / 12, col = (i % 12) * 8;
    gl2lds16(Kb + ((size_t)(b * S_ + r)) * D_ + h * HD_ + col, &Ks[i * 8]);
  }
  __syncthreads();
  const float scale = 0.1020620726f;  // 1/sqrt(96)
  f32x4 p[2][13];
  #pragma unroll
  for (int rep = 0; rep < 2; ++rep) {
    const int ii = wave + rep * 4;
    if (ii >= 7) continue;
    bf16x8 af[3];
    #pragma unroll
    for (int ks = 0; ks < 3; ++ks)
      af[ks] = *(const bf16x8*)(qB + ((size_t)(ii * 16 + c)) * D_ + h * HD_ + ks * 32 + quad * 8);
    __builtin_amdgcn_s_setprio(1);
    #pragma unroll
    for (int j = 0; j < 13; ++j) {
      f32x4 a = {};
      #pragma unroll
      for (int ks = 0; ks < 3; ++ks) {
        bf16x8 bf = *(const bf16x8*)&Ks[(j * 16 + c) * HD_ + ks * 32 + quad * 8];
        a = __builtin_amdgcn_mfma_f32_16x16x32_bf16(af[ks], bf, a, 0, 0, 0);
      }
      p[rep][j] = a;
    }
    __builtin_amdgcn_s_setprio(0);
    float m[4] = {-1e30f, -1e30f, -1e30f, -1e30f};
    #pragma unroll
    for (int j = 0; j < 13; ++j)
      #pragma unroll
      for (int r = 0; r < 4; ++r) {
        float v = p[rep][j][r] * scale;
        if (j == 12 && c >= 4) v = -1e30f;   // mask padded s 196..207 (kills NaN too)
        p[rep][j][r] = v;
        m[r] = fmaxf(m[r], v);
      }
    #pragma unroll
    for (int r = 0; r < 4; ++r) {
      m[r] = fmaxf(m[r], __shfl_xor(m[r], 1));
      m[r] = fmaxf(m[r], __shfl_xor(m[r], 2));
      m[r] = fmaxf(m[r], __shfl_xor(m[r], 4));
      m[r] = fmaxf(m[r], __shfl_xor(m[r], 8));
    }
    float lsum[4] = {0.f, 0.f, 0.f, 0.f};
    #pragma unroll
    for (int j = 0; j < 13; ++j)
      #pragma unroll
      for (int r = 0; r < 4; ++r) {
        float e = __expf(p[rep][j][r] - m[r]);
        p[rep][j][r] = e; lsum[r] += e;
      }
    #pragma unroll
    for (int r = 0; r < 4; ++r) {
      lsum[r] += __shfl_xor(lsum[r], 1);
      lsum[r] += __shfl_xor(lsum[r], 2);
      lsum[r] += __shfl_xor(lsum[r], 4);
      lsum[r] += __shfl_xor(lsum[r], 8);
      lsum[r] = 1.f / lsum[r];
    }
    #pragma unroll
    for (int j = 0; j < 13; ++j)
      #pragma unroll
      for (int r = 0; r < 4; ++r)
        p[rep][j][r] *= lsum[r];
  }
  __syncthreads();   // everyone done reading Ks -> safe to overwrite with Ps
  #pragma unroll
  for (int rep = 0; rep < 2; ++rep) {
    const int ii = wave + rep * 4;
    if (ii >= 7) continue;
    #pragma unroll
    for (int r = 0; r < 4; ++r) {
      const int g = ii * 16 + quad * 4 + r;
      #pragma unroll
      for (int j = 0; j < 13; ++j)
        Ps[g * SP_ + j * 16 + c] = f2bf(p[rep][j][r]);
      Ps[g * SP_ + 208 + c] = 0;   // pad s 208..223
    }
  }
  __syncthreads();
  #pragma unroll
  for (int rep = 0; rep < 2; ++rep) {
    const int ii = wave + rep * 4;
    if (ii >= 7) continue;
    bf16x8 af[7];
    #pragma unroll
    for (int k = 0; k < 7; ++k)
      af[k] = *(const bf16x8*)&Ps[(ii * 16 + c) * SP_ + k * 32 + quad * 8];
    #pragma unroll
    for (int j = 0; j < 6; ++j) {
      f32x4 acc = {};
      __builtin_amdgcn_s_setprio(1);
      #pragma unroll
      for (int k = 0; k < 7; ++k) {
        bf16x8 bf = *(const bf16x8*)(VbT + ((size_t)bh * HD_ + j * 16 + c) * SP_ + k * 32 + quad * 8);
        acc = __builtin_amdgcn_mfma_f32_16x16x32_bf16(af[k], bf, acc, 0, 0, 0);
      }
      __builtin_amdgcn_s_setprio(0);
      #pragma unroll
      for (int r = 0; r < 4; ++r) {
        const int g = ii * 16 + quad * 4 + r;
        if (g < G_)
          ctx[((size_t)(b * G_ + g)) * D_ + h * HD_ + j * 16 + c] = f2bf(acc[r]);
      }
    }
  }
}

// ---------------- residual + LayerNorm (add-input bf16) --------------------
// transb: bf16 out written transposed as [g][b][768] (for the head's A-operand)
__global__ __launch_bounds__(256) void k_lnres(const float* __restrict__ resid, int resid_mod,
    const ushort* __restrict__ addB, const float* __restrict__ gamma, const float* __restrict__ beta,
    float* __restrict__ outf, ushort* __restrict__ outb, int transb) {
  const int row = blockIdx.x, t = threadIdx.x;
  __shared__ float r1[256], r2[256];
  const float* rrow = resid + (size_t)(resid_mod ? (row % G_) : row) * D_;
  const ushort* arow = addB + (size_t)row * D_;
  float y[3]; float s = 0.f, sq = 0.f;
  #pragma unroll
  for (int i = 0; i < 3; ++i) {
    int d = t + i * 256;
    float v = rrow[d] + bf2f(arow[d]);
    y[i] = v; s += v; sq += v * v;
  }
  r1[t] = s; r2[t] = sq; __syncthreads();
  for (int o = 128; o > 0; o >>= 1) { if (t < o) { r1[t] += r1[t + o]; r2[t] += r2[t + o]; } __syncthreads(); }
  const float mean = r1[0] * (1.f / D_);
  const float var  = r2[0] * (1.f / D_) - mean * mean;
  const float w = rsqrtf(var + 1e-5f);
  const size_t orow = transb ? ((size_t)(row % G_) * B_ + row / G_) : (size_t)row;
  #pragma unroll
  for (int i = 0; i < 3; ++i) {
    int d = t + i * 256;
    float v = (y[i] - mean) * w * gamma[d] + beta[d];
    if (outf) outf[(size_t)row * D_ + d] = v;
    if (outb) outb[orow * D_ + d] = f2bf(v);
  }
}

// ---------------- grouped head via MFMA, LDS-free, coalesced ---------------
__global__ __launch_bounds__(256) void k_head4(const ushort* __restrict__ hT,
    const ushort* __restrict__ dupT, const float* __restrict__ dup_bias, float* __restrict__ out) {
  const int g = blockIdx.x, j = blockIdx.y, t = threadIdx.x;
  const int lane = t & 63, wave = t >> 6;
  const int quad = lane >> 4, c = lane & 15;
  const ushort* ap = hT + ((size_t)g * B_ + wave * 16 + c) * D_;
  const ushort* bp = dupT + ((size_t)g * FP_ + j * 16 + c) * D_;
  f32x4 acc = {};
  #pragma unroll 8
  for (int k0 = 0; k0 < D_; k0 += 32) {
    bf16x8 af = *(const bf16x8*)(ap + k0 + quad * 8);
    bf16x8 bf = *(const bf16x8*)(bp + k0 + quad * 8);
    acc = __builtin_amdgcn_mfma_f32_16x16x32_bf16(af, bf, acc, 0, 0, 0);
  }
  const int f = j * 16 + c;
  if (f >= DF_) return;
  const int n = g * DF_ + f;
  if (n >= NC_) return;
  const float bv = dup_bias[n];
  #pragma unroll
  for (int r = 0; r < 4; ++r) {
    const int b = wave * 16 + quad * 4 + r;
    out[(size_t)b * NC_ + n] = acc[r] + bv;
  }
}

// ---------------------------------------------------------------------------
// workspace layout (bytes)
// ---------------------------------------------------------------------------
static constexpr size_t OFF_AEMB  = 0;          // bf16 [12544,2048] = 51,380,224
static constexpr size_t OFF_VBT   = 0;          // bf16 [512,96,224]  = 22,020,096
static constexpr size_t OFF_FF    = 0;          // bf16 [6400,2048] = 26,214,400
static constexpr size_t OFF_FFO   = 26214400;   // bf16 [6400,768]  = 9,830,400 (end 36,044,800)
static constexpr size_t OFF_WEMB  = 51380224;   // bf16 3,145,728
static constexpr size_t OFF_MEM   = 54525952;   // bf16 [12544,768] = 19,267,584
static constexpr size_t OFF_WK    = 73793536;   // 1,179,648   (wk|wv contiguous = fused 1536x768)
static constexpr size_t OFF_WV    = 74973184;   // 1,179,648
static constexpr size_t OFF_WO    = 76152832;   // 1,179,648
static constexpr size_t OFF_W1    = 77332480;   // 3,145,728
static constexpr size_t OFF_W2    = 80478208;   // 3,145,728
static constexpr size_t OFF_DUP   = 83623936;   // bf16 [100,112,768] = 17,203,200
static constexpr size_t OFF_KB    = 100827136;  // bf16 [12544,768] = 19,267,584
static constexpr size_t OFF_TGT   = 139362304;  // f32 [100,768] = 307,200
static constexpr size_t OFF_TGTB  = 139669504;  // bf16 [128,768] = 196,608
static constexpr size_t OFF_Q     = 139866112;  // bf16 [128,768] = 196,608
static constexpr size_t OFF_CTX   = 140068864;  // bf16 9,830,400 (also wqB early: dead before attn)
static constexpr size_t OFF_WQ    = OFF_CTX;    // bf16 [768,768] = 1,179,648 (consumed before ctx written)
static constexpr size_t OFF_CTXO  = 149899264;  // bf16 [6400,768] = 9,830,400
static constexpr size_t OFF_TGT2F = 169560064;  // f32 19,660,800
static constexpr size_t OFF_TGT2B = 189220864;  // bf16 9,830,400
static constexpr size_t OFF_HB    = 199051264;  // bf16 [100,64,768] = 9,830,400 (end 208,881,664)

extern "C" void kernel_launch(void* const* d_in, const int* in_sizes, int n_in,
                              void* d_out, int out_size, void* d_ws, size_t ws_size,
                              hipStream_t stream) {
  const float* x           = (const float*)d_in[0];
  const float* w_embed     = (const float*)d_in[1];
  const float* b_embed     = (const float*)d_in[2];
  const float* query_embed = (const float*)d_in[3];
  const float* wq          = (const float*)d_in[4];
  const float* bq          = (const float*)d_in[5];
  const float* wk          = (const float*)d_in[6];
  const float* bk          = (const float*)d_in[7];
  const float* wv          = (const float*)d_in[8];
  const float* bv          = (const float*)d_in[9];
  const float* wo          = (const float*)d_in[10];
  const float* bo          = (const float*)d_in[11];
  const float* g1          = (const float*)d_in[12];
  const float* be1         = (const float*)d_in[13];
  const float* g2          = (const float*)d_in[14];
  const float* be2         = (const float*)d_in[15];
  const float* g3          = (const float*)d_in[16];
  const float* be3         = (const float*)d_in[17];
  const float* w1          = (const float*)d_in[18];
  const float* bl1         = (const float*)d_in[19];
  const float* w2          = (const float*)d_in[20];
  const float* bl2         = (const float*)d_in[21];
  const float* dup_pool    = (const float*)d_in[22];
  const float* dup_bias    = (const float*)d_in[23];
  float* out = (float*)d_out;
  char* ws = (char*)d_ws;

  ushort* aemb  = (ushort*)(ws + OFF_AEMB);
  ushort* wembB = (ushort*)(ws + OFF_WEMB);
  ushort* memB  = (ushort*)(ws + OFF_MEM);
  ushort* wkvB  = (ushort*)(ws + OFF_WK);    // fused [1536][768]
  ushort* wkB   = (ushort*)(ws + OFF_WK);
  ushort* wvB   = (ushort*)(ws + OFF_WV);
  ushort* woB   = (ushort*)(ws + OFF_WO);
  ushort* w1B   = (ushort*)(ws + OFF_W1);
  ushort* w2B   = (ushort*)(ws + OFF_W2);
  ushort* wqB   = (ushort*)(ws + OFF_WQ);
  ushort* dupT  = (ushort*)(ws + OFF_DUP);
  ushort* Kb    = (ushort*)(ws + OFF_KB);
  float*  tgtF  = (float*)(ws + OFF_TGT);
  ushort* tgtB  = (ushort*)(ws + OFF_TGTB);
  ushort* qB    = (ushort*)(ws + OFF_Q);
  ushort* VbT   = (ushort*)(ws + OFF_VBT);
  ushort* ctxB  = (ushort*)(ws + OFF_CTX);
  ushort* ctxoB = (ushort*)(ws + OFF_CTXO);
  float*  tgt2F = (float*)(ws + OFF_TGT2F);
  ushort* tgt2B = (ushort*)(ws + OFF_TGT2B);
  ushort* ffB   = (ushort*)(ws + OFF_FF);
  ushort* ffoB  = (ushort*)(ws + OFF_FFO);
  ushort* hT    = (ushort*)(ws + OFF_HB);

  // 1. prep: x-transpose + wemb/wq cvt + tgt LN (only what embed needs)
  PrepArgs pa;
  pa.x = x; pa.aemb = aemb;
  pa.csrc[0] = w_embed; pa.cdst[0] = wembB; pa.cn4[0] = D_ * CIN_ / 8;
  pa.csrc[1] = wq;      pa.cdst[1] = wqB;   pa.cn4[1] = D_ * D_ / 8;
  pa.ctotal = pa.cn4[0] + pa.cn4[1];
  pa.qe = query_embed; pa.g1 = g1; pa.be1 = be1; pa.tgt = tgtF; pa.tgtB = tgtB;
  k_prep<<<XP_BLKS + CVP_BLKS + TG_BLKS, 256, 0, stream>>>(pa);

  // 2. embed dispatch: dupT + embed GEMM (+relu) + q-proj + wk/wv/wo/w1/w2 cvt
  EmbArgs ea;
  ea.aemb = aemb; ea.wembB = wembB; ea.b_embed = b_embed; ea.memB = memB;
  ea.tgtB = tgtB; ea.wqB = wqB; ea.bq = bq; ea.qB = qB;
  ea.dup = dup_pool; ea.dupT = dupT;
  ea.csrc[0] = wk; ea.cdst[0] = wkB; ea.cn4[0] = D_ * D_ / 8;
  ea.csrc[1] = wv; ea.cdst[1] = wvB; ea.cn4[1] = D_ * D_ / 8;
  ea.csrc[2] = wo; ea.cdst[2] = woB; ea.cn4[2] = D_ * D_ / 8;
  ea.csrc[3] = w1; ea.cdst[3] = w1B; ea.cn4[3] = FF_ * D_ / 8;
  ea.csrc[4] = w2; ea.cdst[4] = w2B; ea.cn4[4] = D_ * FF_ / 8;
  ea.ctotal = ea.cn4[0] + ea.cn4[1] + ea.cn4[2] + ea.cn4[3] + ea.cn4[4];
  k_embed<<<DT2_BLKS + EG_BLKS + QP_BLKS + CV2_BLKS, 256, 0, stream>>>(ea);

  // 3. fused K|V projection: K -> Kb [12544,768], V -> VbT [512][96][224] transposed
  k_gemm<<<swz_grid(98, 12), 256, 0, stream>>>(memB, wkvB, bk, bv, nullptr, Kb, VbT,
                                               D_, D_, 12, 98, 0);

  // 4. fused attention (QK^T + softmax + PV)
  k_attn<<<dim3(NH_, B_), 256, 0, stream>>>(qB, Kb, VbT, ctxB);

  // 5. ctx @ wo^T + bo -> bf16 [6400, 768] (64-row tiles)
  k_gemm64<<<swz_grid(100, 6), 256, 0, stream>>>(ctxB, woB, bo, ctxoB, D_, D_, 6, 100, 0);

  // 6. tgt2 = LN(tgt + ctxo)
  k_lnres<<<BG_, 256, 0, stream>>>(tgtF, 1, ctxoB, g2, be2, tgt2F, tgt2B, 0);

  // 7-8. FFN
  k_gemm<<<swz_grid(50, 16), 256, 0, stream>>>(tgt2B, w1B, bl1, nullptr, nullptr, ffB, nullptr,
                                               FF_, D_, 16, 50, 1);
  k_gemm64<<<swz_grid(100, 6), 256, 0, stream>>>(ffB, w2B, bl2, ffoB, D_, FF_, 6, 100, 0);

  // 9. h = LN(tgt2 + ffo) -> bf16 transposed [g][64][768]
  k_lnres<<<BG_, 256, 0, stream>>>(tgt2F, 0, ffoB, g3, be3, nullptr, hT, 1);

  // 10. grouped head -> logits fp32 [64, 9605] via MFMA (coalesced, LDS-free)
  k_head4<<<dim3(G_, 7), 256, 0, stream>>>(hT, dupT, dup_bias, out);
}